// Round 12
// baseline (54.486 us; speedup 1.0000x reference)
//
#include <hip/hip_runtime.h>

namespace {

constexpr int BATCH = 4, SEQ = 4096, DM = 256, DP = 80, NCH = 16;
constexpr float ALPHA = 0.1f;

__device__ __forceinline__ float dot4(float4 a, float4 b) {
  return a.x * b.x + a.y * b.y + a.z * b.z + a.w * b.w;
}
__device__ __forceinline__ float dot16f4(const float4* __restrict__ R,
                                         const float4* V) {
  float a0 = 0.f, a1 = 0.f, a2 = 0.f, a3 = 0.f;
#pragma unroll
  for (int q = 0; q < 16; q += 4) {
    a0 += dot4(R[q + 0], V[q + 0]); a1 += dot4(R[q + 1], V[q + 1]);
    a2 += dot4(R[q + 2], V[q + 2]); a3 += dot4(R[q + 3], V[q + 3]);
  }
  return (a0 + a1) + (a2 + a3);
}
// fused: one row slice dotted against two vectors (loads shared)
__device__ __forceinline__ void dot16f4_2(const float4* __restrict__ R,
                                          const float4* V1, const float4* V2,
                                          float& o1, float& o2) {
  float a0 = 0.f, a1 = 0.f, b0 = 0.f, b1 = 0.f;
#pragma unroll
  for (int q = 0; q < 16; q += 2) {
    const float4 m0 = R[q], m1 = R[q + 1];
    a0 += dot4(m0, V1[q]); a1 += dot4(m1, V1[q + 1]);
    b0 += dot4(m0, V2[q]); b1 += dot4(m1, V2[q + 1]);
  }
  o1 = a0 + a1; o2 = b0 + b1;
}
__device__ __forceinline__ float dot32f4(const float* __restrict__ r,
                                         const float* v) {
  const float4* R = reinterpret_cast<const float4*>(r);
  const float4* V = reinterpret_cast<const float4*>(v);
  return dot16f4(R, V) + dot16f4(R + 16, V + 16);
}
__device__ __forceinline__ float dot64f4(const float* __restrict__ r,
                                         const float* v) {
  const float4* R = reinterpret_cast<const float4*>(r);
  const float4* V = reinterpret_cast<const float4*>(v);
  float a0 = 0.f, a1 = 0.f, a2 = 0.f, a3 = 0.f;
#pragma unroll 16
  for (int q = 0; q < 64; q += 4) {
    a0 += dot4(R[q + 0], V[q + 0]); a1 += dot4(R[q + 1], V[q + 1]);
    a2 += dot4(R[q + 2], V[q + 2]); a3 += dot4(R[q + 3], V[q + 3]);
  }
  return (a0 + a1) + (a2 + a3);
}
__device__ __forceinline__ float wave_red(float s) {
  s += __shfl_down(s, 32); s += __shfl_down(s, 16); s += __shfl_down(s, 8);
  s += __shfl_down(s, 4);  s += __shfl_down(s, 2);  s += __shfl_down(s, 1);
  return s;
}
// Mt^T v over rows [i0,i0+cnt): a += v[i]*M[i*DM+k], 4 accumulators
__device__ __forceinline__ float colacc(const float* __restrict__ M,
                                        const float* v, int k, int i0, int cnt) {
  float a0 = 0.f, a1 = 0.f, a2 = 0.f, a3 = 0.f;
  const float* p = M + (size_t)i0 * DM + k;
#pragma unroll 4
  for (int i = 0; i < cnt; i += 4) {
    a0 += v[i0 + i + 0] * p[(size_t)(i + 0) * DM];
    a1 += v[i0 + i + 1] * p[(size_t)(i + 1) * DM];
    a2 += v[i0 + i + 2] * p[(size_t)(i + 2) * DM];
    a3 += v[i0 + i + 3] * p[(size_t)(i + 3) * DM];
  }
  return (a0 + a1) + (a2 + a3);
}

// ---------------------------------------------------------------------------
// K1 (R11-proven, verbatim): [0,231) factor rows (7 roles x 33);
// [231,359) x^T x; 359 eo; 360 w1.
// ---------------------------------------------------------------------------
__global__ __launch_bounds__(256, 2)
void k_pre(const float* __restrict__ x, const float* __restrict__ Wemb,
           const float* __restrict__ bemb, const float* __restrict__ Wq,
           const float* __restrict__ Wk, const float* __restrict__ Wv,
           const float* __restrict__ Wout,
           float* __restrict__ Xp, float* __restrict__ cp,
           float* __restrict__ F0r, float* __restrict__ P0r,
           float* __restrict__ K0r, float* __restrict__ P1r,
           float* __restrict__ K1r, float* __restrict__ PF1r,
           float* __restrict__ KF1r, float* __restrict__ w1g,
           float* __restrict__ eog) {
  const int bid = blockIdx.x, t = threadIdx.x;
  __shared__ __align__(16) float esT[512];
  __shared__ __align__(16) float fsT[512];
  __shared__ __align__(16) float4 ppA[4][64];
  __shared__ __align__(16) float4 ppB[4][64];
  __shared__ __align__(16) float xs[2][16][64];
  __shared__ __align__(16) float cs[16][64];
  __shared__ __align__(16) float vbuf[256];

  if (bid < 231) {
    const int role = bid / 33, grp = bid % 33;
    const int r0 = grp * 2, nr = (r0 == 64) ? 1 : 2;
    {
      const float v0 = (r0 < 64) ? Wemb[(size_t)r0 * DM + t] : bemb[t];
      float v1 = 0.f;
      if (nr == 2) v1 = (r0 + 1 < 64) ? Wemb[(size_t)(r0 + 1) * DM + t] : bemb[t];
      esT[t * 2] = v0; esT[t * 2 + 1] = v1;
    }
    __syncthreads();
    const int jg = t & 63, ks = t >> 6, j0 = jg * 4;

    auto nt_pass = [&](const float* src, const float* __restrict__ M,
                       float* dstT, float* dstR) {
      float4 A0 = make_float4(0.f, 0.f, 0.f, 0.f);
      float4 A1 = make_float4(0.f, 0.f, 0.f, 0.f);
      const float* Mp = M + (size_t)(ks * 64) * DM + j0;
#pragma unroll 16
      for (int i = 0; i < 64; ++i) {
        const float4 m = *reinterpret_cast<const float4*>(Mp + (size_t)i * DM);
        const float s0 = src[(ks * 64 + i) * 2];
        const float s1 = src[(ks * 64 + i) * 2 + 1];
        A0.x += s0 * m.x; A0.y += s0 * m.y; A0.z += s0 * m.z; A0.w += s0 * m.w;
        A1.x += s1 * m.x; A1.y += s1 * m.y; A1.z += s1 * m.z; A1.w += s1 * m.w;
      }
      ppA[ks][jg] = A0; ppB[ks][jg] = A1;
      __syncthreads();
      if (t < 128) {
        const int rr = t >> 6, jj = t & 63;
        float4 q0, q1, q2, q3;
        if (rr == 0) { q0 = ppA[0][jj]; q1 = ppA[1][jj]; q2 = ppA[2][jj]; q3 = ppA[3][jj]; }
        else         { q0 = ppB[0][jj]; q1 = ppB[1][jj]; q2 = ppB[2][jj]; q3 = ppB[3][jj]; }
        const float4 s = make_float4((q0.x + q1.x) + (q2.x + q3.x),
                                     (q0.y + q1.y) + (q2.y + q3.y),
                                     (q0.z + q1.z) + (q2.z + q3.z),
                                     (q0.w + q1.w) + (q2.w + q3.w));
        if (dstT) {
          dstT[(jj * 4 + 0) * 2 + rr] = s.x;
          dstT[(jj * 4 + 1) * 2 + rr] = s.y;
          dstT[(jj * 4 + 2) * 2 + rr] = s.z;
          dstT[(jj * 4 + 3) * 2 + rr] = s.w;
        }
        if (dstR && rr < nr)
          *reinterpret_cast<float4*>(&dstR[(size_t)(r0 + rr) * DM + jj * 4]) = s;
      }
      __syncthreads();
    };

    const float* Wq1 = Wq + (size_t)DM * DM;
    const float* Wk1 = Wk + (size_t)DM * DM;
    float* dstR;
    if (role == 0)      { dstR = F0r;  nt_pass(esT, Wv,  nullptr, dstR); }
    else if (role == 1) { dstR = P0r;  nt_pass(esT, Wq,  nullptr, dstR); }
    else if (role == 2) { dstR = K0r;  nt_pass(esT, Wk,  nullptr, dstR); }
    else if (role == 3) { dstR = P1r;  nt_pass(esT, Wq1, nullptr, dstR); }
    else if (role == 4) { dstR = K1r;  nt_pass(esT, Wk1, nullptr, dstR); }
    else if (role == 5) {
      dstR = PF1r;
      nt_pass(esT, Wv, fsT, nullptr);
      nt_pass(fsT, Wq1, nullptr, dstR);
    } else {
      dstR = KF1r;
      nt_pass(esT, Wv, fsT, nullptr);
      nt_pass(fsT, Wk1, nullptr, dstR);
    }
    if (grp == 32) {
      for (int rr = 65; rr < DP; ++rr) dstR[(size_t)rr * DM + t] = 0.f;
    }
  } else if (bid < 359) {
    const int idx = bid - 231;
    const int per_b = NCH * 2;
    const int b = idx / per_b, r5 = idx % per_b, ch = r5 >> 1, half = r5 & 1;
    const int chrows = SEQ / NCH, nstage = chrows / 16;
    const float* xb = x + ((size_t)b * SEQ + (size_t)ch * chrows) * 64;
    const int trs = t >> 4, tcs = t & 15;
    const int tr2 = t >> 3, tc2 = t & 7;

    float acc[2][4] = {{0.f, 0.f, 0.f, 0.f}, {0.f, 0.f, 0.f, 0.f}};
    float4 csum = make_float4(0.f, 0.f, 0.f, 0.f);
    float4 v = *reinterpret_cast<const float4*>(xb + (size_t)trs * 64 + tcs * 4);
    int buf = 0;
    for (int st = 0; st < nstage; ++st) {
      *reinterpret_cast<float4*>(&xs[buf][trs][tcs * 4]) = v;
      csum.x += v.x; csum.y += v.y; csum.z += v.z; csum.w += v.w;
      __syncthreads();
      float4 vn = make_float4(0.f, 0.f, 0.f, 0.f);
      if (st + 1 < nstage)
        vn = *reinterpret_cast<const float4*>(
            xb + (size_t)((st + 1) * 16 + trs) * 64 + tcs * 4);
#pragma unroll
      for (int s = 0; s < 16; ++s) {
        const float a0 = xs[buf][s][tr2 * 2 + 0];
        const float a1 = xs[buf][s][tr2 * 2 + 1];
        const float4 b4 =
            *reinterpret_cast<const float4*>(&xs[buf][s][half * 32 + tc2 * 4]);
        acc[0][0] += a0 * b4.x; acc[0][1] += a0 * b4.y;
        acc[0][2] += a0 * b4.z; acc[0][3] += a0 * b4.w;
        acc[1][0] += a1 * b4.x; acc[1][1] += a1 * b4.y;
        acc[1][2] += a1 * b4.z; acc[1][3] += a1 * b4.w;
      }
      v = vn; buf ^= 1;
    }
    float* Xpb = Xp + (size_t)(b * NCH + ch) * 4096;
#pragma unroll
    for (int rr = 0; rr < 2; ++rr) {
      const float4 s4 = make_float4(acc[rr][0], acc[rr][1], acc[rr][2], acc[rr][3]);
      *reinterpret_cast<float4*>(
          &Xpb[(size_t)(tr2 * 2 + rr) * 64 + half * 32 + tc2 * 4]) = s4;
    }
    if (half == 0) {
      *reinterpret_cast<float4*>(&cs[trs][tcs * 4]) = csum;
      __syncthreads();
      if (t < 64) {
        float s = 0.f;
#pragma unroll
        for (int g = 0; g < 16; ++g) s += cs[g][t];
        cp[(size_t)(b * NCH + ch) * 64 + t] = s;
      }
    }
  } else if (bid == 359) {
    vbuf[t] = Wout[t];
    __syncthreads();
    if (t < 160) {
      const int i = t >> 1, s = t & 1;
      const float* row = (i < 64) ? Wemb + (size_t)i * DM : (i == 64) ? bemb : nullptr;
      float a = row ? dot32f4(row + s * 128, vbuf + s * 128) : 0.f;
      a += __shfl_down(a, 1);
      if (s == 0) eog[i] = a;
    }
  } else {
    vbuf[t] = Wout[t];
    __syncthreads();
    const float* Wv1 = Wv + (size_t)DM * DM;
    w1g[t] = dot64f4(Wv1 + (size_t)t * DM, vbuf);
  }
}

// ---------------------------------------------------------------------------
// K2 (4 blocks x 1024): per-batch everything, factor-form chain, 11 steps.
// ---------------------------------------------------------------------------
__global__ __launch_bounds__(1024, 4)
void k_post(const float* __restrict__ Xp, const float* __restrict__ cp,
            const float* __restrict__ Wemb, const float* __restrict__ bemb,
            const float* __restrict__ Wout,
            const float* __restrict__ F0r, const float* __restrict__ P0r,
            const float* __restrict__ K0r, const float* __restrict__ P1r,
            const float* __restrict__ K1r, const float* __restrict__ PF1r,
            const float* __restrict__ KF1r, const float* __restrict__ w1g,
            const float* __restrict__ eog, const float* __restrict__ bout,
            float* __restrict__ out) {
  const int b = blockIdx.x, t = threadIdx.x;
  __shared__ __align__(16) float X[80][84];
  __shared__ __align__(16) float vA[256], vP1[256], vF[256], vB[256], vC[256];
  __shared__ __align__(16) float w1l[256], wol[256];
  __shared__ __align__(16) float cl[DP], eo[DP], e1[DP], f1[DP], f0[DP];
  __shared__ __align__(16) float cM0[DP], g8[DP], y8[DP], qv[DP];
  __shared__ __align__(16) float rE[DP], rF[DP], t1v[DP], Xq[DP];
  __shared__ __align__(16) float pr1[DP], pr2[DP];
  __shared__ float dots[2], d0s;

  // ---- T0: X core 16-deep reduce || cl || stage w1l/wol/eo || zero X pads
  if (t < 512) {
    const int e = t * 8;
    const float* base = Xp + (size_t)b * NCH * 4096 + e;
    float4 aA = make_float4(0.f, 0.f, 0.f, 0.f), aB = aA;
#pragma unroll 4
    for (int ch = 0; ch < NCH; ++ch) {
      const float4 p1 = *reinterpret_cast<const float4*>(base + (size_t)ch * 4096);
      const float4 p2 = *reinterpret_cast<const float4*>(base + (size_t)ch * 4096 + 4);
      aA.x += p1.x; aA.y += p1.y; aA.z += p1.z; aA.w += p1.w;
      aB.x += p2.x; aB.y += p2.y; aB.z += p2.z; aB.w += p2.w;
    }
    const int r = t >> 3, c = (t & 7) * 8;
    *reinterpret_cast<float4*>(&X[r][c]) = aA;
    *reinterpret_cast<float4*>(&X[r][c + 4]) = aB;
  } else if (t < 576) {
    const int i = t - 512;
    const float* cb = cp + (size_t)b * NCH * 64 + i;
    float v0 = 0.f, v1 = 0.f, v2 = 0.f, v3 = 0.f;
#pragma unroll
    for (int ch = 0; ch < NCH; ch += 4) {
      v0 += cb[(size_t)(ch + 0) * 64]; v1 += cb[(size_t)(ch + 1) * 64];
      v2 += cb[(size_t)(ch + 2) * 64]; v3 += cb[(size_t)(ch + 3) * 64];
    }
    cl[i] = (v0 + v1) + (v2 + v3);
    if (i == 0) cl[64] = (float)SEQ;
    if (i == 1) for (int p = 65; p < DP; ++p) cl[p] = 0.f;
  } else if (t < 640) {
    reinterpret_cast<float4*>(w1l)[t - 576] =
        reinterpret_cast<const float4*>(w1g)[t - 576];
  } else if (t < 704) {
    reinterpret_cast<float4*>(wol)[t - 640] =
        reinterpret_cast<const float4*>(Wout)[t - 640];
  } else if (t < 784) {
    eo[t - 704] = eog[t - 704];
  } else {
    for (int m = t - 784; m < 2160; m += 240) {
      if (m < 960) X[m / 15][65 + m % 15] = 0.f;
      else { const int q = m - 960; X[65 + q / 80][q % 80] = 0.f; }
    }
  }
  __syncthreads();

  // ---- T1: e1 = Ebar@w1 || f1 = F0@w1 || f0 = F0@wo || X borders
  if (t < 320) {
    const int i = t >> 2, s = t & 3;
    const float* row = (i < 64) ? Wemb + (size_t)i * DM : (i == 64) ? bemb : nullptr;
    float a = row ? dot16f4(reinterpret_cast<const float4*>(row + s * 64),
                            reinterpret_cast<const float4*>(w1l + s * 64)) : 0.f;
    a += __shfl_down(a, 2); a += __shfl_down(a, 1);
    if (s == 0) e1[i] = a;
  } else if (t < 640) {
    const int u = t - 320, i = u >> 2, s = u & 3;
    float a = dot16f4(reinterpret_cast<const float4*>(F0r + (size_t)i * DM + s * 64),
                      reinterpret_cast<const float4*>(w1l + s * 64));
    a += __shfl_down(a, 2); a += __shfl_down(a, 1);
    if (s == 0) f1[i] = a;
  } else if (t < 960) {
    const int u = t - 640, i = u >> 2, s = u & 3;
    float a = dot16f4(reinterpret_cast<const float4*>(F0r + (size_t)i * DM + s * 64),
                      reinterpret_cast<const float4*>(wol + s * 64));
    a += __shfl_down(a, 2); a += __shfl_down(a, 1);
    if (s == 0) f0[i] = a;
  } else {
    for (int m = t - 960; m < 129; m += 64) {
      if (m < 64) X[m][64] = cl[m];
      else if (m < 128) X[64][m - 64] = cl[m - 64];
      else X[64][64] = (float)SEQ;
    }
  }
  __syncthreads();

  // ---- T2: vA = P0^T cl || vP1 = P1^T cl  (2-way i-sliced column walks)
  {
    const int u = (t < 512) ? t : t - 512;
    const int k = u >> 1, s = u & 1;
    const float* M = (t < 512) ? P0r : P1r;
    float a = colacc(M, cl, k, s * 40, 40);
    a += __shfl_down(a, 1);
    if (s == 0) { if (t < 512) vA[k] = a; else vP1[k] = a; }
  }
  __syncthreads();

  // ---- T3: cM0 = K0@vA || y = X.f1 || dot0 = cl.eo
  if (t < 320) {
    const int j = t >> 2, s = t & 3;
    float a = dot16f4(reinterpret_cast<const float4*>(K0r + (size_t)j * DM + s * 64),
                      reinterpret_cast<const float4*>(vA + s * 64));
    a += __shfl_down(a, 2); a += __shfl_down(a, 1);
    if (s == 0) cM0[j] = a;
  } else if (t < 640) {
    const int u = t - 320, i = u >> 2, s = u & 3;
    float a = 0.f;
    for (int j = s * 20; j < s * 20 + 20; ++j) a += X[i][j] * f1[j];
    a += __shfl_down(a, 2); a += __shfl_down(a, 1);
    if (s == 0) y8[i] = a;
  } else if (t < 704) {
    const int l = t - 640;
    float v = cl[l] * eo[l] + ((l < 16) ? cl[64 + l] * eo[64 + l] : 0.f);
    v = wave_red(v);
    if (l == 0) d0s = v;
  }
  __syncthreads();

  // ---- T4: g = cM0.X (LDS) || vB = K0^T y (2-way sliced)
  if (t < 320) {
    const int j = t >> 2, s = t & 3;
    float a = 0.f;
    for (int i = s * 20; i < s * 20 + 20; ++i) a += cM0[i] * X[i][j];
    a += __shfl_down(a, 2); a += __shfl_down(a, 1);
    if (s == 0) g8[j] = a;
  } else if (t < 832) {
    const int u = t - 320, k = u >> 1, s = u & 1;
    float a = colacc(K0r, y8, k, s * 40, 40);
    a += __shfl_down(a, 1);
    if (s == 0) vB[k] = a;
  }
  __syncthreads();

  // ---- T5: vF = PF1^T g (4-way sliced, all lanes)
  {
    const int k = t >> 2, s = t & 3;
    float a = colacc(PF1r, g8, k, s * 20, 20);
    a += __shfl_down(a, 2); a += __shfl_down(a, 1);
    if (s == 0) vF[k] = a;
  }
  __syncthreads();

  // ---- T6: rE = K1@(vP1 + a vF) || rF = KF1@(...) || qv = e1 + a P0@vB
  if (t < 320) {
    const int j = t >> 2, s = t & 3;
    float a1, a2;
    dot16f4_2(reinterpret_cast<const float4*>(K1r + (size_t)j * DM + s * 64),
              reinterpret_cast<const float4*>(vP1 + s * 64),
              reinterpret_cast<const float4*>(vF + s * 64), a1, a2);
    float a = a1 + ALPHA * a2;
    a += __shfl_down(a, 2); a += __shfl_down(a, 1);
    if (s == 0) rE[j] = a;
  } else if (t < 640) {
    const int u = t - 320, j = u >> 2, s = u & 3;
    float a1, a2;
    dot16f4_2(reinterpret_cast<const float4*>(KF1r + (size_t)j * DM + s * 64),
              reinterpret_cast<const float4*>(vP1 + s * 64),
              reinterpret_cast<const float4*>(vF + s * 64), a1, a2);
    float a = a1 + ALPHA * a2;
    a += __shfl_down(a, 2); a += __shfl_down(a, 1);
    if (s == 0) rF[j] = a;
  } else if (t < 960) {
    const int u = t - 640, j = u >> 2, s = u & 3;
    float a = dot16f4(reinterpret_cast<const float4*>(P0r + (size_t)j * DM + s * 64),
                      reinterpret_cast<const float4*>(vB + s * 64));
    a += __shfl_down(a, 2); a += __shfl_down(a, 1);
    if (s == 0) qv[j] = e1[j] + ALPHA * a;
  }
  __syncthreads();

  // ---- T7: t1 = rF.X || Xq = X.qv || pr1 = g*f0
  if (t < 320) {
    const int j = t >> 2, s = t & 3;
    float a = 0.f;
    for (int i = s * 20; i < s * 20 + 20; ++i) a += rF[i] * X[i][j];
    a += __shfl_down(a, 2); a += __shfl_down(a, 1);
    if (s == 0) t1v[j] = a;
  } else if (t < 640) {
    const int u = t - 320, i = u >> 2, s = u & 3;
    float a = 0.f;
    for (int j = s * 20; j < s * 20 + 20; ++j) a += X[i][j] * qv[j];
    a += __shfl_down(a, 2); a += __shfl_down(a, 1);
    if (s == 0) Xq[i] = a;
  } else if (t < 720) {
    const int i = t - 640; pr1[i] = g8[i] * f0[i];
  }
  __syncthreads();

  // ---- T8: vC = K0^T t1 (4-way sliced)
  {
    const int k = t >> 2, s = t & 3;
    float a = colacc(K0r, t1v, k, s * 20, 20);
    a += __shfl_down(a, 2); a += __shfl_down(a, 1);
    if (s == 0) vC[k] = a;
  }
  __syncthreads();

  // ---- T9: pr2 = (rE + a P0@vC) * Xq
  if (t < 320) {
    const int j = t >> 2, s = t & 3;
    float a = dot16f4(reinterpret_cast<const float4*>(P0r + (size_t)j * DM + s * 64),
                      reinterpret_cast<const float4*>(vC + s * 64));
    a += __shfl_down(a, 2); a += __shfl_down(a, 1);
    if (s == 0) pr2[j] = (rE[j] + ALPHA * a) * Xq[j];
  }
  __syncthreads();

  // ---- T10: reduce + out
  const int w = t >> 6, l = t & 63;
  if (w < 2) {
    const float* pr = (w == 0) ? pr1 : pr2;
    float v = pr[l] + ((l < 16) ? pr[64 + l] : 0.f);
    v = wave_red(v);
    if (l == 0) dots[w] = v;
  }
  __syncthreads();
  if (t == 0) out[b] = d0s + ALPHA * dots[0] + ALPHA * dots[1] + bout[0];
}

}  // namespace

extern "C" void kernel_launch(void* const* d_in, const int* in_sizes, int n_in,
                              void* d_out, int out_size, void* d_ws, size_t ws_size,
                              hipStream_t stream) {
  const float* x    = (const float*)d_in[0];
  const float* Wemb = (const float*)d_in[1];
  const float* bemb = (const float*)d_in[2];
  const float* Wq   = (const float*)d_in[3];
  const float* Wk   = (const float*)d_in[4];
  const float* Wv   = (const float*)d_in[5];
  const float* Wout = (const float*)d_in[6];
  const float* bout = (const float*)d_in[7];
  float* out = (float*)d_out;

  float* p = (float*)d_ws;
  float* Xp   = p; p += (size_t)BATCH * NCH * 4096;
  float* cp   = p; p += (size_t)BATCH * NCH * 64;
  float* F0r  = p; p += DP * 256;
  float* P0r  = p; p += DP * 256;
  float* K0r  = p; p += DP * 256;
  float* P1r  = p; p += DP * 256;
  float* K1r  = p; p += DP * 256;
  float* PF1r = p; p += DP * 256;
  float* KF1r = p; p += DP * 256;
  float* w1g  = p; p += 256;
  float* eog  = p; p += DP;

  k_pre<<<361, 256, 0, stream>>>(x, Wemb, bemb, Wq, Wk, Wv, Wout,
                                 Xp, cp, F0r, P0r, K0r, P1r, K1r, PF1r, KF1r,
                                 w1g, eog);
  k_post<<<BATCH, 1024, 0, stream>>>(Xp, cp, Wemb, bemb, Wout,
                                     F0r, P0r, K0r, P1r, K1r, PF1r, KF1r,
                                     w1g, eog, bout, out);
}

// Round 13
// 30.525 us; speedup vs baseline: 1.7850x; 1.7850x over previous
//
#include <hip/hip_runtime.h>

namespace {

constexpr int BATCH = 4, SEQ = 4096, DM = 256, DP = 80, NCH = 16;
constexpr float ALPHA = 0.1f;

__device__ __forceinline__ float dot4(float4 a, float4 b) {
  return a.x * b.x + a.y * b.y + a.z * b.z + a.w * b.w;
}
__device__ __forceinline__ float dot5f4(const float* __restrict__ r,
                                        const float* v) {
  const float4* R = reinterpret_cast<const float4*>(r);
  const float4* V = reinterpret_cast<const float4*>(v);
  return ((dot4(R[0], V[0]) + dot4(R[1], V[1])) +
          (dot4(R[2], V[2]) + dot4(R[3], V[3]))) + dot4(R[4], V[4]);
}
__device__ __forceinline__ float dot10f4(const float* __restrict__ r,
                                         const float* v) {
  const float4* R = reinterpret_cast<const float4*>(r);
  const float4* V = reinterpret_cast<const float4*>(v);
  float a0 = 0.f, a1 = 0.f;
#pragma unroll
  for (int q = 0; q < 10; q += 2) {
    a0 += dot4(R[q], V[q]); a1 += dot4(R[q + 1], V[q + 1]);
  }
  return a0 + a1;
}
__device__ __forceinline__ float dot16f4(const float4* __restrict__ R,
                                         const float4* V) {
  float a0 = 0.f, a1 = 0.f, a2 = 0.f, a3 = 0.f;
#pragma unroll
  for (int q = 0; q < 16; q += 4) {
    a0 += dot4(R[q + 0], V[q + 0]); a1 += dot4(R[q + 1], V[q + 1]);
    a2 += dot4(R[q + 2], V[q + 2]); a3 += dot4(R[q + 3], V[q + 3]);
  }
  return (a0 + a1) + (a2 + a3);
}
__device__ __forceinline__ float dot32f4(const float* __restrict__ r,
                                         const float* v) {
  const float4* R = reinterpret_cast<const float4*>(r);
  const float4* V = reinterpret_cast<const float4*>(v);
  return dot16f4(R, V) + dot16f4(R + 16, V + 16);
}
__device__ __forceinline__ float dot64f4(const float* __restrict__ r,
                                         const float* v) {
  const float4* R = reinterpret_cast<const float4*>(r);
  const float4* V = reinterpret_cast<const float4*>(v);
  float a0 = 0.f, a1 = 0.f, a2 = 0.f, a3 = 0.f;
#pragma unroll 16
  for (int q = 0; q < 64; q += 4) {
    a0 += dot4(R[q + 0], V[q + 0]); a1 += dot4(R[q + 1], V[q + 1]);
    a2 += dot4(R[q + 2], V[q + 2]); a3 += dot4(R[q + 3], V[q + 3]);
  }
  return (a0 + a1) + (a2 + a3);
}
__device__ __forceinline__ float wave_red(float s) {
  s += __shfl_down(s, 32); s += __shfl_down(s, 16); s += __shfl_down(s, 8);
  s += __shfl_down(s, 4);  s += __shfl_down(s, 2);  s += __shfl_down(s, 1);
  return s;
}

// ---------------------------------------------------------------------------
// K1 (R11-proven, verbatim): [0,231) factor rows (7 roles x 33);
// [231,359) x^T x; 359 eo; 360 w1.
// ---------------------------------------------------------------------------
__global__ __launch_bounds__(256, 2)
void k_pre(const float* __restrict__ x, const float* __restrict__ Wemb,
           const float* __restrict__ bemb, const float* __restrict__ Wq,
           const float* __restrict__ Wk, const float* __restrict__ Wv,
           const float* __restrict__ Wout,
           float* __restrict__ Xp, float* __restrict__ cp,
           float* __restrict__ F0r, float* __restrict__ P0r,
           float* __restrict__ K0r, float* __restrict__ P1r,
           float* __restrict__ K1r, float* __restrict__ PF1r,
           float* __restrict__ KF1r, float* __restrict__ w1g,
           float* __restrict__ eog) {
  const int bid = blockIdx.x, t = threadIdx.x;
  __shared__ __align__(16) float esT[512];
  __shared__ __align__(16) float fsT[512];
  __shared__ __align__(16) float4 ppA[4][64];
  __shared__ __align__(16) float4 ppB[4][64];
  __shared__ __align__(16) float xs[2][16][64];
  __shared__ __align__(16) float cs[16][64];
  __shared__ __align__(16) float vbuf[256];

  if (bid < 231) {
    const int role = bid / 33, grp = bid % 33;
    const int r0 = grp * 2, nr = (r0 == 64) ? 1 : 2;
    {
      const float v0 = (r0 < 64) ? Wemb[(size_t)r0 * DM + t] : bemb[t];
      float v1 = 0.f;
      if (nr == 2) v1 = (r0 + 1 < 64) ? Wemb[(size_t)(r0 + 1) * DM + t] : bemb[t];
      esT[t * 2] = v0; esT[t * 2 + 1] = v1;
    }
    __syncthreads();
    const int jg = t & 63, ks = t >> 6, j0 = jg * 4;

    auto nt_pass = [&](const float* src, const float* __restrict__ M,
                       float* dstT, float* dstR) {
      float4 A0 = make_float4(0.f, 0.f, 0.f, 0.f);
      float4 A1 = make_float4(0.f, 0.f, 0.f, 0.f);
      const float* Mp = M + (size_t)(ks * 64) * DM + j0;
#pragma unroll 16
      for (int i = 0; i < 64; ++i) {
        const float4 m = *reinterpret_cast<const float4*>(Mp + (size_t)i * DM);
        const float s0 = src[(ks * 64 + i) * 2];
        const float s1 = src[(ks * 64 + i) * 2 + 1];
        A0.x += s0 * m.x; A0.y += s0 * m.y; A0.z += s0 * m.z; A0.w += s0 * m.w;
        A1.x += s1 * m.x; A1.y += s1 * m.y; A1.z += s1 * m.z; A1.w += s1 * m.w;
      }
      ppA[ks][jg] = A0; ppB[ks][jg] = A1;
      __syncthreads();
      if (t < 128) {
        const int rr = t >> 6, jj = t & 63;
        float4 q0, q1, q2, q3;
        if (rr == 0) { q0 = ppA[0][jj]; q1 = ppA[1][jj]; q2 = ppA[2][jj]; q3 = ppA[3][jj]; }
        else         { q0 = ppB[0][jj]; q1 = ppB[1][jj]; q2 = ppB[2][jj]; q3 = ppB[3][jj]; }
        const float4 s = make_float4((q0.x + q1.x) + (q2.x + q3.x),
                                     (q0.y + q1.y) + (q2.y + q3.y),
                                     (q0.z + q1.z) + (q2.z + q3.z),
                                     (q0.w + q1.w) + (q2.w + q3.w));
        if (dstT) {
          dstT[(jj * 4 + 0) * 2 + rr] = s.x;
          dstT[(jj * 4 + 1) * 2 + rr] = s.y;
          dstT[(jj * 4 + 2) * 2 + rr] = s.z;
          dstT[(jj * 4 + 3) * 2 + rr] = s.w;
        }
        if (dstR && rr < nr)
          *reinterpret_cast<float4*>(&dstR[(size_t)(r0 + rr) * DM + jj * 4]) = s;
      }
      __syncthreads();
    };

    const float* Wq1 = Wq + (size_t)DM * DM;
    const float* Wk1 = Wk + (size_t)DM * DM;
    float* dstR;
    if (role == 0)      { dstR = F0r;  nt_pass(esT, Wv,  nullptr, dstR); }
    else if (role == 1) { dstR = P0r;  nt_pass(esT, Wq,  nullptr, dstR); }
    else if (role == 2) { dstR = K0r;  nt_pass(esT, Wk,  nullptr, dstR); }
    else if (role == 3) { dstR = P1r;  nt_pass(esT, Wq1, nullptr, dstR); }
    else if (role == 4) { dstR = K1r;  nt_pass(esT, Wk1, nullptr, dstR); }
    else if (role == 5) {
      dstR = PF1r;
      nt_pass(esT, Wv, fsT, nullptr);
      nt_pass(fsT, Wq1, nullptr, dstR);
    } else {
      dstR = KF1r;
      nt_pass(esT, Wv, fsT, nullptr);
      nt_pass(fsT, Wk1, nullptr, dstR);
    }
    if (grp == 32) {
      for (int rr = 65; rr < DP; ++rr) dstR[(size_t)rr * DM + t] = 0.f;
    }
  } else if (bid < 359) {
    const int idx = bid - 231;
    const int per_b = NCH * 2;
    const int b = idx / per_b, r5 = idx % per_b, ch = r5 >> 1, half = r5 & 1;
    const int chrows = SEQ / NCH, nstage = chrows / 16;
    const float* xb = x + ((size_t)b * SEQ + (size_t)ch * chrows) * 64;
    const int trs = t >> 4, tcs = t & 15;
    const int tr2 = t >> 3, tc2 = t & 7;

    float acc[2][4] = {{0.f, 0.f, 0.f, 0.f}, {0.f, 0.f, 0.f, 0.f}};
    float4 csum = make_float4(0.f, 0.f, 0.f, 0.f);
    float4 v = *reinterpret_cast<const float4*>(xb + (size_t)trs * 64 + tcs * 4);
    int buf = 0;
    for (int st = 0; st < nstage; ++st) {
      *reinterpret_cast<float4*>(&xs[buf][trs][tcs * 4]) = v;
      csum.x += v.x; csum.y += v.y; csum.z += v.z; csum.w += v.w;
      __syncthreads();
      float4 vn = make_float4(0.f, 0.f, 0.f, 0.f);
      if (st + 1 < nstage)
        vn = *reinterpret_cast<const float4*>(
            xb + (size_t)((st + 1) * 16 + trs) * 64 + tcs * 4);
#pragma unroll
      for (int s = 0; s < 16; ++s) {
        const float a0 = xs[buf][s][tr2 * 2 + 0];
        const float a1 = xs[buf][s][tr2 * 2 + 1];
        const float4 b4 =
            *reinterpret_cast<const float4*>(&xs[buf][s][half * 32 + tc2 * 4]);
        acc[0][0] += a0 * b4.x; acc[0][1] += a0 * b4.y;
        acc[0][2] += a0 * b4.z; acc[0][3] += a0 * b4.w;
        acc[1][0] += a1 * b4.x; acc[1][1] += a1 * b4.y;
        acc[1][2] += a1 * b4.z; acc[1][3] += a1 * b4.w;
      }
      v = vn; buf ^= 1;
    }
    float* Xpb = Xp + (size_t)(b * NCH + ch) * 4096;
#pragma unroll
    for (int rr = 0; rr < 2; ++rr) {
      const float4 s4 = make_float4(acc[rr][0], acc[rr][1], acc[rr][2], acc[rr][3]);
      *reinterpret_cast<float4*>(
          &Xpb[(size_t)(tr2 * 2 + rr) * 64 + half * 32 + tc2 * 4]) = s4;
    }
    if (half == 0) {
      *reinterpret_cast<float4*>(&cs[trs][tcs * 4]) = csum;
      __syncthreads();
      if (t < 64) {
        float s = 0.f;
#pragma unroll
        for (int g = 0; g < 16; ++g) s += cs[g][t];
        cp[(size_t)(b * NCH + ch) * 64 + t] = s;
      }
    }
  } else if (bid == 359) {
    vbuf[t] = Wout[t];
    __syncthreads();
    if (t < 160) {
      const int i = t >> 1, s = t & 1;
      const float* row = (i < 64) ? Wemb + (size_t)i * DM : (i == 64) ? bemb : nullptr;
      float a = row ? dot32f4(row + s * 128, vbuf + s * 128) : 0.f;
      a += __shfl_down(a, 1);
      if (s == 0) eog[i] = a;
    }
  } else {
    vbuf[t] = Wout[t];
    __syncthreads();
    const float* Wv1 = Wv + (size_t)DM * DM;
    w1g[t] = dot64f4(Wv1 + (size_t)t * DM, vbuf);
  }
}

// ---------------------------------------------------------------------------
// K_mid (471 blocks):
//  [0,4): per-batch head (slim): cl reduce; then dot0 = cl.eo || Xg
//         borders+pads || clg.
//  [4,68): X-reduce into Xg core
//  [68,468): composites: mat=(bid-68)/80, j=(bid-68)%80:
//   0: C0[j][i]=C0T[i][j]=P0_i.K0_j ; 1: C1[j][i]=P1_i.K1_j ;
//   2: CY[j][i]=PF1_i.K1_j ; 3: D1[j][i]=P1_i.KF1_j ; 4: DY[j][i]=PF1_i.KF1_j
//  [468,471): aux: e1=Ebar@w1 ; f1=F0@w1 ; f0=F0@Wout
// ---------------------------------------------------------------------------
__global__ __launch_bounds__(256, 2)
void k_mid(const float* __restrict__ Xp, const float* __restrict__ cp,
           const float* __restrict__ Wemb, const float* __restrict__ bemb,
           const float* __restrict__ Wout,
           const float* __restrict__ F0r, const float* __restrict__ P0r,
           const float* __restrict__ K0r, const float* __restrict__ P1r,
           const float* __restrict__ K1r, const float* __restrict__ PF1r,
           const float* __restrict__ KF1r, const float* __restrict__ w1g,
           const float* __restrict__ eog,
           float* __restrict__ C0, float* __restrict__ C0T,
           float* __restrict__ C1, float* __restrict__ CY,
           float* __restrict__ D1, float* __restrict__ DY,
           float* __restrict__ Xg, float* __restrict__ clg,
           float* __restrict__ dot0g, float* __restrict__ e1g,
           float* __restrict__ f1g, float* __restrict__ f0g) {
  const int bid = blockIdx.x, t = threadIdx.x;
  __shared__ __align__(16) float bvs[256];
  __shared__ __align__(16) float clS[DP], eoS[DP];

  if (bid < 4) {
    const int b = bid;
    // step1: cl reduce (+pads), stage eo
    if (t < 64) {
      const float* cb = cp + (size_t)b * NCH * 64 + t;
      float v0 = 0.f, v1 = 0.f, v2 = 0.f, v3 = 0.f;
#pragma unroll
      for (int ch = 0; ch < NCH; ch += 4) {
        v0 += cb[(size_t)(ch + 0) * 64]; v1 += cb[(size_t)(ch + 1) * 64];
        v2 += cb[(size_t)(ch + 2) * 64]; v3 += cb[(size_t)(ch + 3) * 64];
      }
      clS[t] = (v0 + v1) + (v2 + v3);
    } else if (t == 64) clS[64] = (float)SEQ;
    else if (t < 80) clS[t] = 0.f;
    else if (t >= 128 && t < 208) eoS[t - 128] = eog[t - 128];
    __syncthreads();
    // step2: dot0 = cl.eo || Xg borders + pads || clg
    if (t >= 192) {
      const int l = t - 192;
      float v = clS[l] * eoS[l] + ((l < 16) ? clS[64 + l] * eoS[64 + l] : 0.f);
      v = wave_red(v);
      if (l == 0) dot0g[b] = v;
    }
    float* XB = Xg + (size_t)b * 6480;
    for (int n = t; n < 2384; n += 256) {
      if (n < 64) XB[n * 81 + 64] = clS[n];
      else if (n < 128) XB[64 * 81 + (n - 64)] = clS[n - 64];
      else if (n == 128) XB[64 * 81 + 64] = (float)SEQ;
      else if (n < 1169) {
        const int m = n - 129;
        XB[(m >> 4) * 81 + 65 + (m & 15)] = 0.f;
      } else {
        const int m = n - 1169;
        XB[(65 + m / 81) * 81 + m % 81] = 0.f;
      }
    }
    if (t < 80) clg[b * DP + t] = clS[t];
  } else if (bid < 68) {
    const int idx = bid - 4;
    const int b = idx >> 4, sl = idx & 15;
    const int e = sl * 256 + t;
    const float* base = Xp + (size_t)b * NCH * 4096 + e;
    float a0 = 0.f, a1 = 0.f, a2 = 0.f, a3 = 0.f;
#pragma unroll
    for (int ch = 0; ch < NCH; ch += 4) {
      a0 += base[(size_t)(ch + 0) * 4096]; a1 += base[(size_t)(ch + 1) * 4096];
      a2 += base[(size_t)(ch + 2) * 4096]; a3 += base[(size_t)(ch + 3) * 4096];
    }
    Xg[(size_t)b * 6480 + (e >> 6) * 81 + (e & 63)] = (a0 + a1) + (a2 + a3);
  } else if (bid < 468) {
    const int mat = (bid - 68) / 80, j = (bid - 68) % 80;
    const float* bsrc = (mat == 0) ? K0r : (mat < 3) ? K1r : KF1r;
    bvs[t] = bsrc[(size_t)j * DM + t];
    __syncthreads();
    if (t < 160) {
      const int i = t >> 1, s = t & 1;
      const float* A = (mat == 0) ? P0r : (mat == 1 || mat == 3) ? P1r : PF1r;
      float a = dot32f4(A + (size_t)i * DM + s * 128, bvs + s * 128);
      a += __shfl_down(a, 1);
      if (s == 0) {
        if (mat == 0) { C0[j * DP + i] = a; C0T[i * DP + j] = a; }
        else if (mat == 1) C1[j * DP + i] = a;
        else if (mat == 2) CY[j * DP + i] = a;
        else if (mat == 3) D1[j * DP + i] = a;
        else DY[j * DP + i] = a;
      }
    }
  } else {
    const int which = bid - 468;  // 0:e1 1:f1 2:f0
    bvs[t] = (which == 2) ? Wout[t] : w1g[t];
    __syncthreads();
    if (t < 160) {
      const int i = t >> 1, s = t & 1;
      const float* row;
      if (which == 0)
        row = (i < 64) ? Wemb + (size_t)i * DM : (i == 64) ? bemb : nullptr;
      else
        row = (i < 65) ? F0r + (size_t)i * DM : nullptr;
      float a = row ? dot32f4(row + s * 128, bvs + s * 128) : 0.f;
      a += __shfl_down(a, 1);
      if (s == 0) {
        if (which == 0) e1g[i] = a;
        else if (which == 1) f1g[i] = a;
        else f0g[i] = a;
      }
    }
  }
}

// ---------------------------------------------------------------------------
// K_post (4 blocks x 1024): 7-step chain.
// ---------------------------------------------------------------------------
__global__ __launch_bounds__(1024, 4)
void k_post(const float* __restrict__ Xg, const float* __restrict__ clg,
            const float* __restrict__ dot0g, const float* __restrict__ C0,
            const float* __restrict__ C0T, const float* __restrict__ C1,
            const float* __restrict__ CY, const float* __restrict__ D1,
            const float* __restrict__ DY, const float* __restrict__ e1g,
            const float* __restrict__ f1g, const float* __restrict__ f0g,
            const float* __restrict__ bout, float* __restrict__ out) {
  const int b = blockIdx.x, t = threadIdx.x;
  __shared__ __align__(16) float X[80][81];
  __shared__ __align__(16) float cl[DP], cM0[DP], e1[DP], f1[DP], f0[DP];
  __shared__ __align__(16) float g8[DP], y8[DP], qv[DP];
  __shared__ __align__(16) float rE[DP], rF[DP], t1v[DP], Xq[DP];
  __shared__ __align__(16) float pr1[DP], pr2[DP];
  __shared__ float dots[2], d0s;

  // ---- T0: load Xg (f4 flat) + vectors
  {
    float* Xf = &X[0][0];
    const float4* src = reinterpret_cast<const float4*>(Xg + (size_t)b * 6480);
    float4* dst = reinterpret_cast<float4*>(Xf);
    for (int n = t; n < 1620; n += 1024) dst[n] = src[n];
    if (t < 80) cl[t] = clg[b * DP + t];
    else if (t < 160) e1[t - 80] = e1g[t - 80];
    else if (t < 240) f1[t - 160] = f1g[t - 160];
    else if (t < 320) f0[t - 240] = f0g[t - 240];
    else if (t == 1023) d0s = dot0g[b];
  }
  __syncthreads();

  // ---- T1: cM0 = C0.cl || y = X.f1
  if (t < 320) {
    const int j = t >> 2, s = t & 3;
    float a = dot5f4(C0 + j * DP + s * 20, cl + s * 20);
    a += __shfl_down(a, 2); a += __shfl_down(a, 1);
    if (s == 0) cM0[j] = a;
  } else if (t < 640) {
    const int u = t - 320, i = u >> 2, s = u & 3;
    float a = 0.f;
    for (int j = s * 20; j < s * 20 + 20; ++j) a += X[i][j] * f1[j];
    a += __shfl_down(a, 2); a += __shfl_down(a, 1);
    if (s == 0) y8[i] = a;
  }
  __syncthreads();

  // ---- T2 (LDS): g = cM0.X
  if (t < 320) {
    const int j = t >> 2, s = t & 3;
    float a = 0.f;
    for (int i = s * 20; i < s * 20 + 20; ++i) a += cM0[i] * X[i][j];
    a += __shfl_down(a, 2); a += __shfl_down(a, 1);
    if (s == 0) g8[j] = a;
  }
  __syncthreads();

  // ---- T3: rE = C1.cl + a CY.g || rF = D1.cl + a DY.g || qv = e1 + a C0T.y
  if (t < 320) {
    const int j = t >> 2, s = t & 3;
    float a = (s < 2) ? dot10f4(C1 + j * DP + s * 40, cl + s * 40)
                      : ALPHA * dot10f4(CY + j * DP + (s - 2) * 40, g8 + (s - 2) * 40);
    a += __shfl_down(a, 2); a += __shfl_down(a, 1);
    if (s == 0) rE[j] = a;
  } else if (t < 640) {
    const int u = t - 320, j = u >> 2, s = u & 3;
    float a = (s < 2) ? dot10f4(D1 + j * DP + s * 40, cl + s * 40)
                      : ALPHA * dot10f4(DY + j * DP + (s - 2) * 40, g8 + (s - 2) * 40);
    a += __shfl_down(a, 2); a += __shfl_down(a, 1);
    if (s == 0) rF[j] = a;
  } else if (t < 960) {
    const int u = t - 640, j = u >> 2, s = u & 3;
    float a = dot5f4(C0T + j * DP + s * 20, y8 + s * 20);
    a += __shfl_down(a, 2); a += __shfl_down(a, 1);
    if (s == 0) qv[j] = e1[j] + ALPHA * a;
  }
  __syncthreads();

  // ---- T4 (LDS): t1 = rF.X || Xq = X.qv || pr1 = g*f0
  if (t < 320) {
    const int j = t >> 2, s = t & 3;
    float a = 0.f;
    for (int i = s * 20; i < s * 20 + 20; ++i) a += rF[i] * X[i][j];
    a += __shfl_down(a, 2); a += __shfl_down(a, 1);
    if (s == 0) t1v[j] = a;
  } else if (t < 640) {
    const int u = t - 320, i = u >> 2, s = u & 3;
    float a = 0.f;
    for (int j = s * 20; j < s * 20 + 20; ++j) a += X[i][j] * qv[j];
    a += __shfl_down(a, 2); a += __shfl_down(a, 1);
    if (s == 0) Xq[i] = a;
  } else if (t < 720) {
    const int i = t - 640; pr1[i] = g8[i] * f0[i];
  }
  __syncthreads();

  // ---- T5: pr2 = (rE + a C0T.t1) * Xq
  if (t < 320) {
    const int j = t >> 2, s = t & 3;
    float a = dot5f4(C0T + j * DP + s * 20, t1v + s * 20);
    a += __shfl_down(a, 2); a += __shfl_down(a, 1);
    if (s == 0) pr2[j] = (rE[j] + ALPHA * a) * Xq[j];
  }
  __syncthreads();

  // ---- T6: reduce + out
  const int w = t >> 6, l = t & 63;
  if (w < 2) {
    const float* pr = (w == 0) ? pr1 : pr2;
    float v = pr[l] + ((l < 16) ? pr[64 + l] : 0.f);
    v = wave_red(v);
    if (l == 0) dots[w] = v;
  }
  __syncthreads();
  if (t == 0) out[b] = d0s + ALPHA * dots[0] + ALPHA * dots[1] + bout[0];
}

}  // namespace

extern "C" void kernel_launch(void* const* d_in, const int* in_sizes, int n_in,
                              void* d_out, int out_size, void* d_ws, size_t ws_size,
                              hipStream_t stream) {
  const float* x    = (const float*)d_in[0];
  const float* Wemb = (const float*)d_in[1];
  const float* bemb = (const float*)d_in[2];
  const float* Wq   = (const float*)d_in[3];
  const float* Wk   = (const float*)d_in[4];
  const float* Wv   = (const float*)d_in[5];
  const float* Wout = (const float*)d_in[6];
  const float* bout = (const float*)d_in[7];
  float* out = (float*)d_out;

  float* p = (float*)d_ws;
  float* Xp   = p; p += (size_t)BATCH * NCH * 4096;
  float* cp   = p; p += (size_t)BATCH * NCH * 64;
  float* F0r  = p; p += DP * 256;
  float* P0r  = p; p += DP * 256;
  float* K0r  = p; p += DP * 256;
  float* P1r  = p; p += DP * 256;
  float* K1r  = p; p += DP * 256;
  float* PF1r = p; p += DP * 256;
  float* KF1r = p; p += DP * 256;
  float* w1g  = p; p += 256;
  float* eog  = p; p += DP;
  float* e1g  = p; p += DP;
  float* f1g  = p; p += DP;
  float* f0g  = p; p += DP;
  float* C0   = p; p += DP * DP;
  float* C0T  = p; p += DP * DP;
  float* C1   = p; p += DP * DP;
  float* CY   = p; p += DP * DP;
  float* D1   = p; p += DP * DP;
  float* DY   = p; p += DP * DP;
  float* Xg   = p; p += (size_t)BATCH * 6480;
  float* clg  = p; p += BATCH * DP;
  float* dot0g = p; p += BATCH;

  k_pre<<<361, 256, 0, stream>>>(x, Wemb, bemb, Wq, Wk, Wv, Wout,
                                 Xp, cp, F0r, P0r, K0r, P1r, K1r, PF1r, KF1r,
                                 w1g, eog);
  k_mid<<<471, 256, 0, stream>>>(Xp, cp, Wemb, bemb, Wout, F0r, P0r, K0r, P1r,
                                 K1r, PF1r, KF1r, w1g, eog, C0, C0T, C1, CY,
                                 D1, DY, Xg, clg, dot0g, e1g, f1g, f0g);
  k_post<<<BATCH, 1024, 0, stream>>>(Xg, clg, dot0g, C0, C0T, C1, CY, D1, DY,
                                     e1g, f1g, f0g, bout, out);
}